// Round 3
// baseline (295.434 us; speedup 1.0000x reference)
//
#include <hip/hip_runtime.h>

#define NROIS 128
#define OUTD  12
#define NVOX  (OUTD * OUTD * OUTD)
#define NCH   64
#define NKEYS (NROIS * NVOX)          // 221184 possible (roi,voxel) keys

// Order-preserving encode of float32 into uint32 for atomicMax.
// f >= 0 -> bits | 0x80000000 ; f < 0 -> ~bits.
// Encoded value of any real float is > 0, so key==0 marks "empty".
__device__ __forceinline__ unsigned enc_f32(float f) {
    unsigned b = __float_as_uint(f);
    return (b & 0x80000000u) ? ~b : (b | 0x80000000u);
}

__device__ __forceinline__ float dec_key(unsigned k) {
    unsigned b = (k & 0x80000000u) ? (k & 0x7fffffffu) : ~k;
    return __uint_as_float(b);
}

// ws layout: [0..15] u32 count (+pad) | [16 ..] u32 flags[NKEYS] | u32 list[NKEYS]
#define WS_FLAGS_OFF 16
#define WS_LIST_OFF  (16 + NKEYS * 4)

// grid = (PBLKS, 128). One ROI per blockIdx.y -> params wave-uniform (SGPRs).
__global__ void __launch_bounds__(256) roi_pool_scatter(
        const float* __restrict__ rois,     // (128, 7)
        const float* __restrict__ pts,      // (P, 3)
        const float* __restrict__ feat,     // (P, 64)
        unsigned*    __restrict__ out,      // (128, 1728, 64) encoded uint keys
        unsigned*    __restrict__ count,
        unsigned*    __restrict__ flags,
        unsigned*    __restrict__ list,
        int npts)
{
    int r = blockIdx.y;
    // Per-block ROI param compute (wave-uniform; identical float ops to
    // the reference sequence so numerics are unchanged).
    float cx = rois[7 * r + 0];
    float cy = rois[7 * r + 1];
    float cz = rois[7 * r + 2];
    float dx = rois[7 * r + 3];
    float dy = rois[7 * r + 4];
    float dz = rois[7 * r + 5];
    float nrz = -rois[7 * r + 6];
    float ca = cosf(nrz);
    float sa = sinf(nrz);
    float hx = __fmul_rn(dx, 0.5f);
    float hy = __fmul_rn(dy, 0.5f);
    float hz = __fmul_rn(dz, 0.5f);
    float vx = __fdiv_rn(dx, 12.0f);
    float vy = __fdiv_rn(dy, 12.0f);
    float vz = __fdiv_rn(dz, 12.0f);

    int stride = gridDim.x * blockDim.x;
    for (int p = blockIdx.x * blockDim.x + threadIdx.x; p < npts; p += stride) {
        float px = pts[3 * p + 0];
        float py = pts[3 * p + 1];
        float pz = pts[3 * p + 2];

        float sx = __fsub_rn(px, cx);
        float sy = __fsub_rn(py, cy);
        float sz = __fsub_rn(pz, cz);
        float lx = __fsub_rn(__fmul_rn(sx, ca), __fmul_rn(sy, sa));
        float ly = __fadd_rn(__fmul_rn(sx, sa), __fmul_rn(sy, ca));

        bool in_box = (lx > -hx) && (lx < hx) &&
                      (ly > -hy) && (ly < hy) &&
                      (fabsf(__fsub_rn(sz, hz)) <= hz);
        if (!in_box) continue;

        int xi = (int)floorf(__fdiv_rn(__fadd_rn(lx, hx), vx));
        int yi = (int)floorf(__fdiv_rn(__fadd_rn(ly, hy), vy));
        int zi = (int)floorf(__fdiv_rn(sz,                vz));
        xi = min(max(xi, 0), OUTD - 1);
        yi = min(max(yi, 0), OUTD - 1);
        zi = min(max(zi, 0), OUTD - 1);

        int key = r * NVOX + xi * (OUTD * OUTD) + yi * OUTD + zi;

        // First toucher of a (roi,voxel) registers it for the decode pass.
        if (atomicExch(&flags[key], 1u) == 0u) {
            unsigned idx = atomicAdd(count, 1u);
            list[idx] = (unsigned)key;
        }

        unsigned* dst = out + (size_t)key * NCH;
        const float* fp = feat + (size_t)p * NCH;
        #pragma unroll
        for (int c = 0; c < NCH; c += 4) {
            float4 v = *reinterpret_cast<const float4*>(fp + c);
            atomicMax(dst + c + 0, enc_f32(v.x));
            atomicMax(dst + c + 1, enc_f32(v.y));
            atomicMax(dst + c + 2, enc_f32(v.z));
            atomicMax(dst + c + 3, enc_f32(v.w));
        }
    }
}

// One wave per touched voxel; lane = channel. Waves beyond *count exit.
__global__ void __launch_bounds__(256) decode_touched(
        unsigned* __restrict__ out,
        const unsigned* __restrict__ count,
        const unsigned* __restrict__ list)
{
    int w    = (blockIdx.x * blockDim.x + threadIdx.x) >> 6;
    int lane = threadIdx.x & 63;
    if (w >= (int)*count) return;
    unsigned key = list[w];
    unsigned* v = out + (size_t)key * NCH;
    unsigned k = v[lane];
    float f = (k == 0u) ? 0.0f : dec_key(k);
    v[lane] = __float_as_uint(f);
}

extern "C" void kernel_launch(void* const* d_in, const int* in_sizes, int n_in,
                              void* d_out, int out_size, void* d_ws, size_t ws_size,
                              hipStream_t stream)
{
    const float* rois = (const float*)d_in[0];
    const float* pts  = (const float*)d_in[1];
    const float* feat = (const float*)d_in[2];
    int npts = in_sizes[1] / 3;

    unsigned* count = (unsigned*)d_ws;
    unsigned* flags = (unsigned*)((char*)d_ws + WS_FLAGS_OFF);
    unsigned* list  = (unsigned*)((char*)d_ws + WS_LIST_OFF);

    // Zero output accumulator (0u == empty == 0.0f bits) and count+flags.
    hipMemsetAsync(d_out, 0, (size_t)out_size * sizeof(float), stream);
    hipMemsetAsync(d_ws, 0, WS_FLAGS_OFF + (size_t)NKEYS * 4, stream);

    dim3 grid(160, NROIS);   // 160*256 threads grid-stride over points, 1 ROI / block.y
    roi_pool_scatter<<<grid, 256, 0, stream>>>(rois, pts, feat,
                                               (unsigned*)d_out, count, flags,
                                               list, npts);

    // Worst case every (roi,voxel) touched: NKEYS waves, 4 waves/block.
    int dblocks = NKEYS / 4;
    decode_touched<<<dblocks, 256, 0, stream>>>((unsigned*)d_out, count, list);
}